// Round 1
// baseline (268.517 us; speedup 1.0000x reference)
//
#include <hip/hip_runtime.h>
#include <math.h>

#define NN 100000
#define NE 1600000
#define FIN 50
#define NC 16

// ---------------------------------------------------------------------------
// Kernel 1: y_l = x @ W_l^T  (to ws), self = x @ W_r^T (to d_out "out" half)
// block = 256 = 16 nodes x 16 classes; W and x rows staged in LDS.
// ---------------------------------------------------------------------------
__global__ __launch_bounds__(256) void lin_kernel(
    const float* __restrict__ x,
    const float* __restrict__ W_l,
    const float* __restrict__ W_r,
    float* __restrict__ y_l,
    float* __restrict__ self_out)
{
    __shared__ float sWl[NC * FIN];
    __shared__ float sWr[NC * FIN];
    __shared__ float sx[16 * FIN];

    const int tid = threadIdx.x;
    for (int i = tid; i < NC * FIN; i += 256) {
        sWl[i] = W_l[i];
        sWr[i] = W_r[i];
    }
    const int node0 = blockIdx.x * 16;
    for (int i = tid; i < 16 * FIN; i += 256) {
        int n = node0 + i / FIN;
        sx[i] = (n < NN) ? x[n * FIN + (i % FIN)] : 0.0f;
    }
    __syncthreads();

    const int ln = tid >> 4;   // local node 0..15
    const int c  = tid & 15;   // class
    const int n  = node0 + ln;
    if (n >= NN) return;

    float accl = 0.0f, accr = 0.0f;
    const float* xr  = &sx[ln * FIN];
    const float* wlr = &sWl[c * FIN];
    const float* wrr = &sWr[c * FIN];
#pragma unroll
    for (int k = 0; k < FIN; ++k) {
        float xv = xr[k];
        accl = fmaf(xv, wlr[k], accl);
        accr = fmaf(xv, wrr[k], accr);
    }
    y_l[n * NC + c]      = accl;
    self_out[n * NC + c] = accr;
}

// ---------------------------------------------------------------------------
// Kernel 2: edge scatter. 16 lanes per edge: lane c atomically adds
// y_l[src*16+c] into agg[tgt*16+c]; lane 0 bumps deg[tgt].
// agg (6.4 MB) + y_l (6.4 MB) are L2-resident.
// ---------------------------------------------------------------------------
__global__ __launch_bounds__(256) void scatter_kernel(
    const int* __restrict__ ei,      // [2, NE] int32: row 0 = src, row 1 = tgt
    const float* __restrict__ y_l,
    float* __restrict__ agg,
    float* __restrict__ deg)
{
    long long gid = (long long)blockIdx.x * blockDim.x + threadIdx.x;
    int e = (int)(gid >> 4);
    int c = (int)(gid & 15);
    if (e >= NE) return;

    int s = ei[e];        // src
    int t = ei[NE + e];   // tgt

    atomicAdd(&agg[t * NC + c], y_l[s * NC + c]);
    if (c == 0) atomicAdd(&deg[t], 1.0f);
}

// ---------------------------------------------------------------------------
// Kernel 3: out = agg/max(deg,1) + b_l + self ; logp = log_softmax(out)
// 16 lanes per node; shfl_xor reductions at width 16.
// ---------------------------------------------------------------------------
__global__ __launch_bounds__(256) void finalize_kernel(
    const float* __restrict__ agg,
    const float* __restrict__ deg,
    const float* __restrict__ b_l,
    float* __restrict__ logp,
    float* __restrict__ outv)   // holds self on entry, final "out" on exit
{
    int tid = blockIdx.x * 256 + threadIdx.x;
    int n = tid >> 4;
    int c = tid & 15;
    if (n >= NN) return;

    float d = deg[n];
    d = fmaxf(d, 1.0f);
    float val = agg[n * NC + c] / d + b_l[c] + outv[n * NC + c];

    float m = val;
#pragma unroll
    for (int off = 1; off < 16; off <<= 1)
        m = fmaxf(m, __shfl_xor(m, off, 16));
    float ex = expf(val - m);
    float ssum = ex;
#pragma unroll
    for (int off = 1; off < 16; off <<= 1)
        ssum += __shfl_xor(ssum, off, 16);

    logp[n * NC + c] = val - m - logf(ssum);
    outv[n * NC + c] = val;
}

extern "C" void kernel_launch(void* const* d_in, const int* in_sizes, int n_in,
                              void* d_out, int out_size, void* d_ws, size_t ws_size,
                              hipStream_t stream) {
    const float* x   = (const float*)d_in[0];
    const int*   ei  = (const int*)d_in[1];
    const float* W_l = (const float*)d_in[2];
    const float* b_l = (const float*)d_in[3];
    const float* W_r = (const float*)d_in[4];

    float* logp = (float*)d_out;                 // [NN*NC]
    float* outv = (float*)d_out + (size_t)NN * NC; // [NN*NC], also "self" scratch

    // ws layout: y_l [NN*NC] | agg [NN*NC] | deg [NN]
    float* y_l = (float*)d_ws;
    float* agg = y_l + (size_t)NN * NC;
    float* deg = agg + (size_t)NN * NC;

    // zero agg + deg (contiguous) — ws is poisoned before every call
    hipMemsetAsync(agg, 0, ((size_t)NN * NC + NN) * sizeof(float), stream);

    lin_kernel<<<(NN + 15) / 16, 256, 0, stream>>>(x, W_l, W_r, y_l, outv);

    long long total = (long long)NE * 16;
    int sblocks = (int)((total + 255) / 256);
    scatter_kernel<<<sblocks, 256, 0, stream>>>(ei, y_l, agg, deg);

    finalize_kernel<<<((NN * NC) + 255) / 256, 256, 0, stream>>>(agg, deg, b_l, logp, outv);
}